// Round 5
// baseline (91.696 us; speedup 1.0000x reference)
//
#include <hip/hip_runtime.h>

#define BATCH 16
#define NPTS  4096
#define TOT   (BATCH * NPTS)     // 65536 points per tensor
#define TWOTOT (2 * TOT)

typedef float f2 __attribute__((ext_vector_type(2)));
typedef float f4 __attribute__((ext_vector_type(4)));

// ---- packed fp32 with op_sel word-broadcast (VOP3P) ----
// t = { p.lo*q.z + q.w , p.hi*q.z + q.w }   (qzw = {z,w} pair)
#define PK_Z(t, p, qzw) \
    asm("v_pk_fma_f32 %0, %1, %2, %2 op_sel:[0,0,1] op_sel_hi:[1,0,1]" \
        : "=v"(t) : "v"(p), "v"(qzw))
// t += p * broadcast(q.hi)
#define PK_HI(t, p, q) \
    asm("v_pk_fma_f32 %0, %1, %2, %0 op_sel:[0,1,0] op_sel_hi:[1,1,1]" \
        : "+v"(t) : "v"(p), "v"(q))
// t += p * broadcast(q.lo)
#define PK_LO(t, p, q) \
    asm("v_pk_fma_f32 %0, %1, %2, %0 op_sel:[0,0,0] op_sel_hi:[1,0,1]" \
        : "+v"(t) : "v"(p), "v"(q))
// acc = min(acc, u, v)
#define MIN3(acc, u, v) \
    asm("v_min3_f32 %0, %1, %2, %0" : "+v"(acc) : "v"(u), "v"(v))

// distance chains for one Q point against BOTH packed P pairs
#define QD(t0, t1, qv)                                          \
    do {                                                        \
        f2 _qxy = __builtin_shufflevector(qv, qv, 0, 1);        \
        f2 _qzw = __builtin_shufflevector(qv, qv, 2, 3);        \
        PK_Z(t0, pz2a, _qzw); PK_HI(t0, py2a, _qxy); PK_LO(t0, px2a, _qxy); \
        PK_Z(t1, pz2b, _qzw); PK_HI(t1, py2b, _qxy); PK_LO(t1, px2b, _qxy); \
    } while (0)

// process 4 Q points (updates acc0..acc3 for the thread's 4 P points)
#define COMP4(q0, q1, q2, q3)                                   \
    do {                                                        \
        f2 tA0, tA1, tB0, tB1;                                  \
        QD(tA0, tA1, q0); QD(tB0, tB1, q1);                     \
        MIN3(acc0, tA0.x, tB0.x); MIN3(acc1, tA0.y, tB0.y);     \
        MIN3(acc2, tA1.x, tB1.x); MIN3(acc3, tA1.y, tB1.y);     \
        QD(tA0, tA1, q2); QD(tB0, tB1, q3);                     \
        MIN3(acc0, tA0.x, tB0.x); MIN3(acc1, tA0.y, tB0.y);     \
        MIN3(acc2, tA1.x, tB1.x); MIN3(acc3, tA1.y, tB1.y);     \
    } while (0)

// Pack {x, y, z, |q|^2} AoS float4 per point; also zero the output scalar.
// pk layout: [2][BATCH][NPTS] f4 ; slot 0 = x tensor, slot 1 = y tensor.
__global__ __launch_bounds__(256) void pack_kernel(const float* __restrict__ x,
                                                   const float* __restrict__ y,
                                                   f4* __restrict__ pk,
                                                   float* __restrict__ out) {
    int idx = blockIdx.x * 256 + threadIdx.x;       // 0 .. 2*TOT-1
    if (idx == 0) out[0] = 0.0f;
    const float* src = (idx < TOT) ? x : y;
    int r = (idx < TOT) ? idx : (idx - TOT);
    float a = src[r * 3 + 0];
    float b = src[r * 3 + 1];
    float c = src[r * 3 + 2];
    f4 v = {a, b, c, fmaf(a, a, fmaf(b, b, c * c))};
    pk[idx] = v;
}

// Pass 1: each thread owns FOUR consecutive P points (2 packed pairs) and
// scans a Q segment with register double-buffering (two 4-Q groups in flight).
// Per Q point: 6 v_pk_fma_f32 + 2 v_min3 => 2.0 VALU/pair, 16 compute-cycles
// per 16B load. Q loads forced to VMEM (broadcast within wave).
template <int QSEGT>
__global__ __launch_bounds__(256) void chamfer_pass1(const f4* __restrict__ pk,
                                                     float* __restrict__ part) {
    constexpr int QLENT = NPTS / QSEGT;
    int qseg  = blockIdx.x >> 7;          // grid = QSEGT * 128
    int chunk = blockIdx.x & 127;

    int pidx0 = chunk * 1024 + threadIdx.x * 4;   // first of 4 P points
    int grp   = pidx0 >> 12;                      // dir*16 + batch (uniform/blk)
    int dir   = grp >> 4;
    int bb    = grp & 15;

    f4 p0 = pk[pidx0 + 0];
    f4 p1 = pk[pidx0 + 1];
    f4 p2 = pk[pidx0 + 2];
    f4 p3 = pk[pidx0 + 3];
    f2 px2a = {-2.0f * p0.x, -2.0f * p1.x}, px2b = {-2.0f * p2.x, -2.0f * p3.x};
    f2 py2a = {-2.0f * p0.y, -2.0f * p1.y}, py2b = {-2.0f * p2.y, -2.0f * p3.y};
    f2 pz2a = {-2.0f * p0.z, -2.0f * p1.z}, pz2b = {-2.0f * p2.z, -2.0f * p3.z};

    int qbase = (1 - dir) * TOT + bb * NPTS + qseg * QLENT;
    const f4* __restrict__ qp = pk + qbase + __shfl(0, 0);  // force VMEM

    float acc0 = 3.4e38f, acc1 = 3.4e38f, acc2 = 3.4e38f, acc3 = 3.4e38f;

    // register double buffer: group A (a0..a3) and group B (b0..b3)
    f4 a0 = qp[0], a1 = qp[1], a2 = qp[2], a3 = qp[3];
    f4 b0 = qp[4], b1 = qp[5], b2 = qp[6], b3 = qp[7];
    qp += 8;
    #pragma unroll 1
    for (int it = 0; it < QLENT / 8 - 1; ++it) {
        COMP4(a0, a1, a2, a3);
        a0 = qp[0]; a1 = qp[1]; a2 = qp[2]; a3 = qp[3];
        COMP4(b0, b1, b2, b3);
        b0 = qp[4]; b1 = qp[5]; b2 = qp[6]; b3 = qp[7];
        qp += 8;
    }
    COMP4(a0, a1, a2, a3);
    COMP4(b0, b1, b2, b3);

    f4 res = {acc0, acc1, acc2, acc3};
    *(f4*)(part + qseg * TWOTOT + pidx0) = res;   // coalesced 16B store
}

// Pass 2: combine segment partials per point, add |p|^2, block-reduce,
// atomic accumulate the mean.
__global__ __launch_bounds__(256) void chamfer_pass2(const float* __restrict__ part,
                                                     const float* __restrict__ pkf,
                                                     float* __restrict__ out,
                                                     int nseg) {
    int gid = blockIdx.x * 256 + threadIdx.x;       // 0..2*TOT-1
    float m = part[gid];
    for (int s = 1; s < nseg; ++s) m = fminf(m, part[s * TWOTOT + gid]);
    float w = pkf[gid * 4 + 3];
    m += w;

    float s = m;
    #pragma unroll
    for (int off = 32; off; off >>= 1) s += __shfl_down(s, off);
    __shared__ float red[4];
    int lane = threadIdx.x & 63, wid = threadIdx.x >> 6;
    if (lane == 0) red[wid] = s;
    __syncthreads();
    if (threadIdx.x == 0) {
        float tot = (red[0] + red[1]) + (red[2] + red[3]);
        atomicAdd(out, tot * (1.0f / (float)TOT));
    }
}

// ---------------- fallback (no workspace): direct form ----------------
__global__ __launch_bounds__(256) void chamfer_direct(const float* __restrict__ x,
                                                      const float* __restrict__ y,
                                                      float* __restrict__ out) {
    int blk   = blockIdx.x;
    int dir   = blk >> 8;
    int t     = blk & 255;
    int b     = t >> 4;
    int chunk = t & 15;

    const float* __restrict__ P = (dir ? y : x) + (b * NPTS + chunk * 256) * 3;
    const float* __restrict__ Q = (dir ? x : y) + b * NPTS * 3;

    float px = P[threadIdx.x * 3 + 0];
    float py = P[threadIdx.x * 3 + 1];
    float pz = P[threadIdx.x * 3 + 2];

    float b0 = 3.4e38f, b1 = 3.4e38f, b2 = 3.4e38f, b3 = 3.4e38f;
    for (int j = 0; j < NPTS; j += 4) {
        #pragma unroll
        for (int u = 0; u < 4; ++u) {
            float dx = px - Q[(j + u) * 3 + 0];
            float dy = py - Q[(j + u) * 3 + 1];
            float dz = pz - Q[(j + u) * 3 + 2];
            float d  = fmaf(dx, dx, fmaf(dy, dy, dz * dz));
            if (u == 0) b0 = fminf(b0, d);
            if (u == 1) b1 = fminf(b1, d);
            if (u == 2) b2 = fminf(b2, d);
            if (u == 3) b3 = fminf(b3, d);
        }
    }
    float best = fminf(fminf(b0, b1), fminf(b2, b3));

    float v = best;
    #pragma unroll
    for (int off = 32; off; off >>= 1) v += __shfl_down(v, off);
    __shared__ float red[4];
    int lane = threadIdx.x & 63, wid = threadIdx.x >> 6;
    if (lane == 0) red[wid] = v;
    __syncthreads();
    if (threadIdx.x == 0) {
        float s = (red[0] + red[1]) + (red[2] + red[3]);
        atomicAdd(out, s * (1.0f / (float)TOT));
    }
}

__global__ void zero_kernel(float* out) { out[0] = 0.0f; }

extern "C" void kernel_launch(void* const* d_in, const int* in_sizes, int n_in,
                              void* d_out, int out_size, void* d_ws, size_t ws_size,
                              hipStream_t stream) {
    const float* x = (const float*)d_in[0];
    const float* y = (const float*)d_in[1];
    float* out = (float*)d_out;

    size_t pk_bytes = (size_t)TWOTOT * 4 * sizeof(float);         // 2 MiB

    if (ws_size >= pk_bytes + (size_t)8 * TWOTOT * sizeof(float)) {
        // QSEG = 8 : part buffer 4 MiB
        float* pkf  = (float*)d_ws;
        float* part = (float*)((char*)d_ws + pk_bytes);
        hipLaunchKernelGGL(pack_kernel, dim3(TWOTOT / 256), dim3(256), 0, stream,
                           x, y, (f4*)pkf, out);
        hipLaunchKernelGGL((chamfer_pass1<8>), dim3(8 * 128), dim3(256), 0, stream,
                           (const f4*)pkf, part);
        hipLaunchKernelGGL(chamfer_pass2, dim3(TWOTOT / 256), dim3(256), 0, stream,
                           part, pkf, out, 8);
    } else if (ws_size >= pk_bytes + (size_t)4 * TWOTOT * sizeof(float)) {
        // QSEG = 4 : part buffer 2 MiB
        float* pkf  = (float*)d_ws;
        float* part = (float*)((char*)d_ws + pk_bytes);
        hipLaunchKernelGGL(pack_kernel, dim3(TWOTOT / 256), dim3(256), 0, stream,
                           x, y, (f4*)pkf, out);
        hipLaunchKernelGGL((chamfer_pass1<4>), dim3(4 * 128), dim3(256), 0, stream,
                           (const f4*)pkf, part);
        hipLaunchKernelGGL(chamfer_pass2, dim3(TWOTOT / 256), dim3(256), 0, stream,
                           part, pkf, out, 4);
    } else {
        hipLaunchKernelGGL(zero_kernel, dim3(1), dim3(1), 0, stream, out);
        hipLaunchKernelGGL(chamfer_direct, dim3(512), dim3(256), 0, stream, x, y, out);
    }
}

// Round 7
// 74.562 us; speedup vs baseline: 1.2298x; 1.2298x over previous
//
#include <hip/hip_runtime.h>
#include <stdint.h>

#define BATCH 16
#define NPTS  4096
#define TOT   (BATCH * NPTS)     // 65536 points per tensor
#define TWOTOT (2 * TOT)

typedef float f2 __attribute__((ext_vector_type(2)));
typedef float f4 __attribute__((ext_vector_type(4)));
typedef uint32_t u32;
typedef u32 u32x4 __attribute__((ext_vector_type(4)));

// ---- packed fp32 with op_sel word-broadcast (VOP3P), verified R4/R5 ----
#define PK_Z(t, p, qzw) \
    asm("v_pk_fma_f32 %0, %1, %2, %2 op_sel:[0,0,1] op_sel_hi:[1,0,1]" \
        : "=v"(t) : "v"(p), "v"(qzw))
#define PK_HI(t, p, q) \
    asm("v_pk_fma_f32 %0, %1, %2, %0 op_sel:[0,1,0] op_sel_hi:[1,1,1]" \
        : "+v"(t) : "v"(p), "v"(q))
#define PK_LO(t, p, q) \
    asm("v_pk_fma_f32 %0, %1, %2, %0 op_sel:[0,0,0] op_sel_hi:[1,0,1]" \
        : "+v"(t) : "v"(p), "v"(q))
#define MIN3(acc, u, v) \
    asm("v_min3_f32 %0, %1, %2, %0" : "+v"(acc) : "v"(u), "v"(v))

// distance chains for one Q point against BOTH packed P pairs
#define QD(t0, t1, qv)                                          \
    do {                                                        \
        f2 _qxy = __builtin_shufflevector(qv, qv, 0, 1);        \
        f2 _qzw = __builtin_shufflevector(qv, qv, 2, 3);        \
        PK_Z(t0, pz2a, _qzw); PK_HI(t0, py2a, _qxy); PK_LO(t0, px2a, _qxy); \
        PK_Z(t1, pz2b, _qzw); PK_HI(t1, py2b, _qxy); PK_LO(t1, px2b, _qxy); \
    } while (0)

#define COMP2(qA, qB)                                           \
    do {                                                        \
        f2 tA0, tA1, tB0, tB1;                                  \
        QD(tA0, tA1, qA); QD(tB0, tB1, qB);                     \
        MIN3(acc0, tA0.x, tB0.x); MIN3(acc1, tA0.y, tB0.y);     \
        MIN3(acc2, tA1.x, tB1.x); MIN3(acc3, tA1.y, tB1.y);     \
    } while (0)

#define COMP8(q0, q1, q2, q3, q4, q5, q6, q7) \
    do { COMP2(q0, q1); COMP2(q2, q3); COMP2(q4, q5); COMP2(q6, q7); } while (0)

// scalar-addressed broadcast load: SRSRC (SGPR quad) + soffset(SGPR) + imm
#define BLOAD(dst, imm) \
    asm volatile("buffer_load_dwordx4 %0, off, %1, %2 offset:" imm \
                 : "=v"(dst) : "s"(rsrc), "s"(soff))

#define LOAD8(r0, r1, r2, r3, r4, r5, r6, r7)                   \
    do {                                                        \
        BLOAD(r0, "0");  BLOAD(r1, "16");  BLOAD(r2, "32");  BLOAD(r3, "48"); \
        BLOAD(r4, "64"); BLOAD(r5, "80");  BLOAD(r6, "96");  BLOAD(r7, "112"); \
        asm volatile("s_add_u32 %0, %0, 128" : "+s"(soff) :: "scc"); \
    } while (0)

// counted wait; ties the 8 buffers as outputs so dependent math can't hoist
// above it; sched_barrier stops the scheduler from crossing (rule #18).
#define WAIT8(cnt, q0, q1, q2, q3, q4, q5, q6, q7)              \
    do {                                                        \
        asm volatile("s_waitcnt vmcnt(" cnt ")"                 \
            : "+v"(q0), "+v"(q1), "+v"(q2), "+v"(q3),           \
              "+v"(q4), "+v"(q5), "+v"(q6), "+v"(q7));          \
        __builtin_amdgcn_sched_barrier(0);                      \
    } while (0)

// Pack {x, y, z, |q|^2} AoS float4 per point; also zero the output scalar.
// pk layout: [2][BATCH][NPTS] f4 ; slot 0 = x tensor, slot 1 = y tensor.
__global__ __launch_bounds__(256) void pack_kernel(const float* __restrict__ x,
                                                   const float* __restrict__ y,
                                                   f4* __restrict__ pk,
                                                   float* __restrict__ out) {
    int idx = blockIdx.x * 256 + threadIdx.x;       // 0 .. 2*TOT-1
    if (idx == 0) out[0] = 0.0f;
    const float* src = (idx < TOT) ? x : y;
    int r = (idx < TOT) ? idx : (idx - TOT);
    float a = src[r * 3 + 0];
    float b = src[r * 3 + 1];
    float c = src[r * 3 + 2];
    f4 v = {a, b, c, fmaf(a, a, fmaf(b, b, c * c))};
    pk[idx] = v;
}

// Pass 1: each thread owns 4 consecutive P points (2 packed pairs), scans its
// Q segment in 8-Q register groups, double-buffered with explicit counted
// vmcnt(8). All Q addressing is scalar (SRSRC + soffset, blockIdx-uniform);
// loop VALU = math only (6 v_pk_fma + 2 v_min3 per 2 Q = 2.0 VALU/pair).
template <int QSEGT>
__global__ __launch_bounds__(256) void chamfer_pass1(const f4* __restrict__ pk,
                                                     float* __restrict__ part) {
    constexpr int QLENT = NPTS / QSEGT;
    constexpr int NG    = QLENT / 8;          // 8-Q groups per segment

    int qseg  = blockIdx.x & (QSEGT - 1);
    int chunk = blockIdx.x / QSEGT;           // 128 chunks of 1024 P points

    // grp is derived from blockIdx ONLY -> structurally wave-uniform (SALU).
    int grp   = chunk >> 2;                   // dir*16 + batch
    int dir   = grp >> 4;
    int bb    = grp & 15;

    int pidx0 = chunk * 1024 + threadIdx.x * 4;

    f4 p0 = pk[pidx0 + 0];
    f4 p1 = pk[pidx0 + 1];
    f4 p2 = pk[pidx0 + 2];
    f4 p3 = pk[pidx0 + 3];
    f2 px2a = {-2.0f * p0.x, -2.0f * p1.x}, px2b = {-2.0f * p2.x, -2.0f * p3.x};
    f2 py2a = {-2.0f * p0.y, -2.0f * p1.y}, py2b = {-2.0f * p2.y, -2.0f * p3.y};
    f2 pz2a = {-2.0f * p0.z, -2.0f * p1.z}, pz2b = {-2.0f * p2.z, -2.0f * p3.z};

    // SRSRC for the Q segment; readfirstlane pins the words to SGPRs.
    union { const f4* p; u32 w[2]; } pu;
    pu.p = pk + (1 - dir) * TOT + bb * NPTS + qseg * QLENT;
    u32 w0 = __builtin_amdgcn_readfirstlane(pu.w[0]);
    u32 w1 = __builtin_amdgcn_readfirstlane(pu.w[1]);
    u32x4 rsrc = { w0, w1, (u32)(QLENT * 16), 0x00020000u };
    u32 soff = 0;

    float acc0 = 3.4e38f, acc1 = 3.4e38f, acc2 = 3.4e38f, acc3 = 3.4e38f;

    f4 a0, a1, a2, a3, a4, a5, a6, a7;
    f4 b0, b1, b2, b3, b4, b5, b6, b7;
    LOAD8(a0, a1, a2, a3, a4, a5, a6, a7);    // G0
    LOAD8(b0, b1, b2, b3, b4, b5, b6, b7);    // G1

    #pragma unroll 1
    for (int it = 0; it < NG / 2 - 1; ++it) {
        WAIT8("8", a0, a1, a2, a3, a4, a5, a6, a7);
        COMP8(a0, a1, a2, a3, a4, a5, a6, a7);
        LOAD8(a0, a1, a2, a3, a4, a5, a6, a7);
        WAIT8("8", b0, b1, b2, b3, b4, b5, b6, b7);
        COMP8(b0, b1, b2, b3, b4, b5, b6, b7);
        LOAD8(b0, b1, b2, b3, b4, b5, b6, b7);
    }
    WAIT8("8", a0, a1, a2, a3, a4, a5, a6, a7);
    COMP8(a0, a1, a2, a3, a4, a5, a6, a7);
    WAIT8("0", b0, b1, b2, b3, b4, b5, b6, b7);
    COMP8(b0, b1, b2, b3, b4, b5, b6, b7);

    f4 res = {acc0, acc1, acc2, acc3};
    *(f4*)(part + qseg * TWOTOT + pidx0) = res;   // coalesced 16B store
}

// Pass 2: 4 points per thread, f4 loads of the partials, add |p|^2,
// block-reduce, one atomic per block.
__global__ __launch_bounds__(256) void chamfer_pass2(const f4* __restrict__ part4,
                                                     const float* __restrict__ pkf,
                                                     float* __restrict__ out,
                                                     int nseg) {
    int t4  = blockIdx.x * 256 + threadIdx.x;     // 0..TWOTOT/4-1
    f4 m = part4[t4];
    for (int s = 1; s < nseg; ++s) {
        f4 v = part4[s * (TWOTOT / 4) + t4];
        m.x = fminf(m.x, v.x); m.y = fminf(m.y, v.y);
        m.z = fminf(m.z, v.z); m.w = fminf(m.w, v.w);
    }
    int gid = t4 * 4;
    float r = (m.x + pkf[(gid + 0) * 4 + 3]) + (m.y + pkf[(gid + 1) * 4 + 3])
            + (m.z + pkf[(gid + 2) * 4 + 3]) + (m.w + pkf[(gid + 3) * 4 + 3]);

    float s = r;
    #pragma unroll
    for (int off = 32; off; off >>= 1) s += __shfl_down(s, off);
    __shared__ float red[4];
    int lane = threadIdx.x & 63, wid = threadIdx.x >> 6;
    if (lane == 0) red[wid] = s;
    __syncthreads();
    if (threadIdx.x == 0) {
        float tot = (red[0] + red[1]) + (red[2] + red[3]);
        atomicAdd(out, tot * (1.0f / (float)TOT));
    }
}

// ---------------- fallback (no workspace): direct form ----------------
__global__ __launch_bounds__(256) void chamfer_direct(const float* __restrict__ x,
                                                      const float* __restrict__ y,
                                                      float* __restrict__ out) {
    int blk   = blockIdx.x;
    int dir   = blk >> 8;
    int t     = blk & 255;
    int b     = t >> 4;
    int chunk = t & 15;

    const float* __restrict__ P = (dir ? y : x) + (b * NPTS + chunk * 256) * 3;
    const float* __restrict__ Q = (dir ? x : y) + b * NPTS * 3;

    float px = P[threadIdx.x * 3 + 0];
    float py = P[threadIdx.x * 3 + 1];
    float pz = P[threadIdx.x * 3 + 2];

    float b0 = 3.4e38f, b1 = 3.4e38f, b2 = 3.4e38f, b3 = 3.4e38f;
    for (int j = 0; j < NPTS; j += 4) {
        #pragma unroll
        for (int u = 0; u < 4; ++u) {
            float dx = px - Q[(j + u) * 3 + 0];
            float dy = py - Q[(j + u) * 3 + 1];
            float dz = pz - Q[(j + u) * 3 + 2];
            float d  = fmaf(dx, dx, fmaf(dy, dy, dz * dz));
            if (u == 0) b0 = fminf(b0, d);
            if (u == 1) b1 = fminf(b1, d);
            if (u == 2) b2 = fminf(b2, d);
            if (u == 3) b3 = fminf(b3, d);
        }
    }
    float best = fminf(fminf(b0, b1), fminf(b2, b3));

    float v = best;
    #pragma unroll
    for (int off = 32; off; off >>= 1) v += __shfl_down(v, off);
    __shared__ float red[4];
    int lane = threadIdx.x & 63, wid = threadIdx.x >> 6;
    if (lane == 0) red[wid] = v;
    __syncthreads();
    if (threadIdx.x == 0) {
        float s = (red[0] + red[1]) + (red[2] + red[3]);
        atomicAdd(out, s * (1.0f / (float)TOT));
    }
}

__global__ void zero_kernel(float* out) { out[0] = 0.0f; }

extern "C" void kernel_launch(void* const* d_in, const int* in_sizes, int n_in,
                              void* d_out, int out_size, void* d_ws, size_t ws_size,
                              hipStream_t stream) {
    const float* x = (const float*)d_in[0];
    const float* y = (const float*)d_in[1];
    float* out = (float*)d_out;

    size_t pk_bytes = (size_t)TWOTOT * 4 * sizeof(float);         // 2 MiB

    if (ws_size >= pk_bytes + (size_t)8 * TWOTOT * sizeof(float)) {
        // QSEG = 8 : part buffer 4 MiB, grid 1024
        float* pkf  = (float*)d_ws;
        float* part = (float*)((char*)d_ws + pk_bytes);
        hipLaunchKernelGGL(pack_kernel, dim3(TWOTOT / 256), dim3(256), 0, stream,
                           x, y, (f4*)pkf, out);
        hipLaunchKernelGGL((chamfer_pass1<8>), dim3(128 * 8), dim3(256), 0, stream,
                           (const f4*)pkf, part);
        hipLaunchKernelGGL(chamfer_pass2, dim3(TWOTOT / 4 / 256), dim3(256), 0, stream,
                           (const f4*)part, pkf, out, 8);
    } else if (ws_size >= pk_bytes + (size_t)4 * TWOTOT * sizeof(float)) {
        // QSEG = 4 : part buffer 2 MiB, grid 512
        float* pkf  = (float*)d_ws;
        float* part = (float*)((char*)d_ws + pk_bytes);
        hipLaunchKernelGGL(pack_kernel, dim3(TWOTOT / 256), dim3(256), 0, stream,
                           x, y, (f4*)pkf, out);
        hipLaunchKernelGGL((chamfer_pass1<4>), dim3(128 * 4), dim3(256), 0, stream,
                           (const f4*)pkf, part);
        hipLaunchKernelGGL(chamfer_pass2, dim3(TWOTOT / 4 / 256), dim3(256), 0, stream,
                           (const f4*)part, pkf, out, 4);
    } else {
        hipLaunchKernelGGL(zero_kernel, dim3(1), dim3(1), 0, stream, out);
        hipLaunchKernelGGL(chamfer_direct, dim3(512), dim3(256), 0, stream, x, y, out);
    }
}